// Round 5
// baseline (312.721 us; speedup 1.0000x reference)
//
#include <hip/hip_runtime.h>
#include <hip/hip_bf16.h>
#include <cstdint>

typedef unsigned short u16;
typedef unsigned int u32;
typedef __bf16 bf16x8 __attribute__((ext_vector_type(8)));
typedef float f32x4 __attribute__((ext_vector_type(4)));

#define BDIM 2
#define TDIM 2048
#define HIDDIM 2048
#define NHEAD 16
#define NKVH 4
#define HD 128
#define MROWS (BDIM*TDIM)     /* 4096 */
#define NQKV 3072
#define KDIM 2048

#define MFMA16(a,b,c) __builtin_amdgcn_mfma_f32_16x16x32_bf16((a),(b),(c),0,0,0)

__device__ __forceinline__ u16 f2bf(float f) {
    __bf16 h = (__bf16)f;
    return __builtin_bit_cast(u16, h);
}
__device__ __forceinline__ float bf2f(u32 u) {
    u <<= 16;
    return __builtin_bit_cast(float, u);
}
__device__ __forceinline__ void gld16(const void* g, void* l) {
    __builtin_amdgcn_global_load_lds(
        (const __attribute__((address_space(1))) u32*)g,
        (__attribute__((address_space(3))) u32*)l, 16, 0, 0);
}

// ---------------- fused prep: x->bf16 convert + 4 weight transposes ----------------
// grid layout: [0,4096) cvt_x | [4096,8192) Wq | [8192,9216) Wk
//              [9216,10240) Wv | [10240,14336) Wo
__global__ __launch_bounds__(256) void prep_kernel(const float* __restrict__ x,
                                                   u16* __restrict__ xb,
                                                   const float* __restrict__ Wq,
                                                   const float* __restrict__ Wk,
                                                   const float* __restrict__ Wv,
                                                   const float* __restrict__ Wo,
                                                   u16* __restrict__ Wqkvt,
                                                   u16* __restrict__ Wot) {
    __shared__ float tile[32][33];
    const int bi = blockIdx.x;
    const int tid = threadIdx.x;
    if (bi < 4096) {
        size_t i = ((size_t)bi * 256 + tid) * 8;
        float4 a = *(const float4*)(x + i);
        float4 b = *(const float4*)(x + i + 4);
        uint4 v;
        v.x = (u32)f2bf(a.x) | ((u32)f2bf(a.y) << 16);
        v.y = (u32)f2bf(a.z) | ((u32)f2bf(a.w) << 16);
        v.z = (u32)f2bf(b.x) | ((u32)f2bf(b.y) << 16);
        v.w = (u32)f2bf(b.z) | ((u32)f2bf(b.w) << 16);
        *(uint4*)(xb + i) = v;
        return;
    }
    const float* src;
    u16* dst;
    int N, n0, k0;
    if (bi < 8192) {
        int t = bi - 4096; src = Wq; dst = Wqkvt; N = 2048;
        n0 = (t & 63) * 32; k0 = (t >> 6) * 32;
    } else if (bi < 9216) {
        int t = bi - 8192; src = Wk; dst = Wqkvt + (size_t)2048 * KDIM; N = 512;
        n0 = (t & 15) * 32; k0 = (t >> 4) * 32;
    } else if (bi < 10240) {
        int t = bi - 9216; src = Wv; dst = Wqkvt + (size_t)2560 * KDIM; N = 512;
        n0 = (t & 15) * 32; k0 = (t >> 4) * 32;
    } else {
        int t = bi - 10240; src = Wo; dst = Wot; N = 2048;
        n0 = (t & 63) * 32; k0 = (t >> 6) * 32;
    }
    const int tx = tid & 31, ty = tid >> 5;   // 32 x 8
#pragma unroll
    for (int r = 0; r < 4; r++)
        tile[ty + 8*r][tx] = src[(size_t)(k0 + ty + 8*r) * N + n0 + tx];
    __syncthreads();
#pragma unroll
    for (int r = 0; r < 4; r++)
        dst[(size_t)(n0 + ty + 8*r) * KDIM + k0 + tx] = f2bf(tile[tx][ty + 8*r]);
}

// ---------------- GEMM: C[m][n] = sum_k A[m][k] * Bt[n][k] ----------------
template<int OUT_BF16>
__global__ void __launch_bounds__(256, 2) gemm_bt(const u16* __restrict__ A,
                                                  const u16* __restrict__ Bt,
                                                  void* __restrict__ C, int ldc) {
    __shared__ __align__(16) u16 Al[128 * 32];
    __shared__ __align__(16) u16 Bl[128 * 32];
    const int tid = threadIdx.x;
    const int lane = tid & 63;
    const int w = tid >> 6;
    const int wm = (w & 1) * 64;
    const int wn = (w >> 1) * 64;
    const int quad = lane >> 4;
    const int l15 = lane & 15;
    const size_t bm = (size_t)blockIdx.x * 128;
    const size_t bn = (size_t)blockIdx.y * 128;

    const int srow = lane >> 2;
    const int kq = (lane & 3) ^ ((lane >> 3) & 3);
    const int i0 = 2 * w, i1 = 2 * w + 1;

    const u16* ga0 = A + (bm + i0*16 + srow) * KDIM + kq * 8;
    const u16* ga1 = A + (bm + i1*16 + srow) * KDIM + kq * 8;
    const u16* gb0 = Bt + (bn + i0*16 + srow) * KDIM + kq * 8;
    const u16* gb1 = Bt + (bn + i1*16 + srow) * KDIM + kq * 8;

    const int swz = ((quad ^ ((l15 >> 1) & 3)) << 3);
    int aoff[4], boff[4];
#pragma unroll
    for (int t = 0; t < 4; t++) {
        aoff[t] = (wm + t*16 + l15) * 32 + swz;
        boff[t] = (wn + t*16 + l15) * 32 + swz;
    }

    f32x4 acc[4][4] = {};

    for (int kt = 0; kt < KDIM / 32; kt++) {
        gld16(ga0 + kt*32, &Al[i0 * 512]);
        gld16(ga1 + kt*32, &Al[i1 * 512]);
        gld16(gb0 + kt*32, &Bl[i0 * 512]);
        gld16(gb1 + kt*32, &Bl[i1 * 512]);
        __syncthreads();
        bf16x8 af[4], bfv[4];
#pragma unroll
        for (int t = 0; t < 4; t++) {
            af[t]  = *(const bf16x8*)&Al[aoff[t]];
            bfv[t] = *(const bf16x8*)&Bl[boff[t]];
        }
#pragma unroll
        for (int mt = 0; mt < 4; mt++)
#pragma unroll
            for (int nt = 0; nt < 4; nt++)
                acc[mt][nt] = MFMA16(af[mt], bfv[nt], acc[mt][nt]);
        __syncthreads();
    }

#pragma unroll
    for (int mt = 0; mt < 4; mt++) {
        size_t m0 = bm + wm + mt*16 + quad*4;
#pragma unroll
        for (int nt = 0; nt < 4; nt++) {
            size_t n = bn + wn + nt*16 + l15;
#pragma unroll
            for (int r = 0; r < 4; r++) {
                if (OUT_BF16)
                    ((u16*)C)[(m0 + r) * (size_t)ldc + n] = f2bf(acc[mt][nt][r]);
                else
                    ((float*)C)[(m0 + r) * (size_t)ldc + n] = acc[mt][nt][r];
            }
        }
    }
}

// ---------------- rotary (in-place on Q and K parts of QKV), Q gets scale folded ----------------
__global__ __launch_bounds__(256) void rotary_kernel(u16* __restrict__ QKV,
                                                     const float* __restrict__ cosT,
                                                     const float* __restrict__ sinT) {
    int i = blockIdx.x * 256 + threadIdx.x;   // < 4096*320
    int m = i / 320;
    int rem = i - m * 320;
    int head = rem >> 4;
    int d0 = (rem & 15) << 2;                 // 0..60
    int t = m & (TDIM - 1);
    int col;
    float sc;
    if (head < NHEAD) {
        col = head * HD + d0;
        sc = 0.08838834764831845f * 1.4426950408889634f; // 1/sqrt(128) * log2(e)
    } else {
        col = HIDDIM + (head - NHEAD) * HD + d0;
        sc = 1.0f;
    }
    u16* p0 = QKV + (size_t)m * NQKV + col;
    u16* p1 = p0 + 64;
    float4 cv = *(const float4*)(cosT + t * HD + d0);
    float4 sv = *(const float4*)(sinT + t * HD + d0);
    uint2 qa = *(const uint2*)p0;
    uint2 qb = *(const uint2*)p1;
    float f0[4] = { bf2f(qa.x & 0xffffu), bf2f(qa.x >> 16), bf2f(qa.y & 0xffffu), bf2f(qa.y >> 16) };
    float f1[4] = { bf2f(qb.x & 0xffffu), bf2f(qb.x >> 16), bf2f(qb.y & 0xffffu), bf2f(qb.y >> 16) };
    float c[4] = { cv.x, cv.y, cv.z, cv.w };
    float s[4] = { sv.x, sv.y, sv.z, sv.w };
    u16 o0[4], o1[4];
#pragma unroll
    for (int k = 0; k < 4; k++) {
        o0[k] = f2bf((f0[k] * c[k] - f1[k] * s[k]) * sc);
        o1[k] = f2bf((f1[k] * c[k] + f0[k] * s[k]) * sc);
    }
    uint2 w0, w1;
    w0.x = (u32)o0[0] | ((u32)o0[1] << 16);
    w0.y = (u32)o0[2] | ((u32)o0[3] << 16);
    w1.x = (u32)o1[0] | ((u32)o1[1] << 16);
    w1.y = (u32)o1[2] | ((u32)o1[3] << 16);
    *(uint2*)p0 = w0;
    *(uint2*)p1 = w1;
}

// ---------------- flash attention, causal, GQA ----------------
// Swapped-operand core (S^T = mfma(K,Q), zero-shuffle PV, lane-local softmax)
// + M-DOUBLING: each wave owns 32 q-rows (two 16-row m-groups), so every LDS
// fragment read (K for QK^T, Vt for PV) feeds TWO MFMAs -> per-q-row LDS
// traffic, staging traffic, barriers, and iteration count all halve.
// QBLK=128 (4 waves x 32 q), KVBLK=64. Tile qt needs nj=2qt+2 KV-iters.
// Grid 512 = 2 blocks/CU; qt = (l>=256) ? 15-pq : pq so co-resident pair
// (l, l+256) under round-robin dispatch sums to exactly 34 iters (balanced).
// Structure = round-3's measured-best: 2 barriers/iter, K dbuf, Vt single.
// LDS = 32K (K dbuf) + 18K (Vt) = 50.2 KB. ~165 VGPR -> 2 waves/SIMD.
__global__ void __launch_bounds__(256, 2) attn_kernel(const u16* __restrict__ QKV,
                                                      u16* __restrict__ AO) {
    constexpr int LV = 72;   // Vt row stride
    __shared__ __align__(16) u16 Kl[2][64 * 128];  // double-buffered K tile
    __shared__ __align__(16) u16 Vt[128 * LV];     // V transposed [d][c(s)]

    const int l  = blockIdx.x;          // 0..511
    const int cc = l & 255;
    const int pq = cc & 7;
    const int h  = (cc >> 3) & 15;
    const int b  = cc >> 7;
    const int qt = (l >> 8) ? (15 - pq) : pq;   // q-tile of 128 rows
    const int nj = 2 * qt + 2;                  // KV-iters (64 each)

    const int kh = h >> 2;
    const int tid = threadIdx.x;
    const int lane = tid & 63;
    const int w = tid >> 6;
    const int quad = lane >> 4;
    const int l15 = lane & 15;

    const size_t rowbase = (size_t)b * TDIM;
    const u16* Qb = QKV + rowbase * NQKV + h * HD;
    const u16* Kb = QKV + rowbase * NQKV + HIDDIM + kh * HD;
    const u16* Vb = Kb + NKVH * HD;

    // K staging: instr i stages rows w*16+i*4..+3; chunk swizzle c ^= (row&7)
    int krow[4], kgch[4];
#pragma unroll
    for (int i = 0; i < 4; i++) {
        krow[i] = w*16 + i*4 + quad;
        kgch[i] = l15 ^ (krow[i] & 7);
    }
    // V staging lane mapping: sp (s-pair), dch (d-chunk of 8)
    const int sp0 = tid & 31, dch0 = tid >> 5, dch1 = dch0 + 8;
    // bit-permuted Vt column: swap s-bit4 with s-bits3:2  (c(s+1)=c(s)+1, s even)
    const int s0v = sp0 * 2;
    const int ccv = (s0v & ~0x1C) | ((s0v & 0x0C) << 1) | ((s0v & 0x10) >> 2);

    // Q fragments: wave w owns rows qt*128 + w*32 + mi*16 + l15, mi in {0,1}
    bf16x8 qf[2][4];
#pragma unroll
    for (int mi = 0; mi < 2; mi++) {
        const u16* qr = Qb + (size_t)(qt*128 + w*32 + mi*16 + l15) * NQKV;
#pragma unroll
        for (int kt = 0; kt < 4; kt++)
            qf[mi][kt] = *(const bf16x8*)(qr + kt*32 + quad*8);
    }
    f32x4 O[2][8] = {};   // O^T: O[mi][nt][r] = O^T[d=nt*16+quad*4+r][q-row mi]
    float mrun[2] = { -1e30f, -1e30f }, lrun[2] = { 0.0f, 0.0f };

    // ---- prologue: prefetch K(0) -> Kl[0], V(0) -> regs ----
#pragma unroll
    for (int i = 0; i < 4; i++)
        gld16(Kb + (size_t)krow[i] * NQKV + kgch[i]*8, &Kl[0][(w*16 + i*4) * 128]);
    uint4 vr0a, vr0b, vr1a, vr1b;
    {
        const u16* g0 = Vb + (size_t)s0v * NQKV + dch0*8;
        vr0a = *(const uint4*)g0;
        vr0b = *(const uint4*)(g0 + NQKV);
        const u16* g1 = Vb + (size_t)s0v * NQKV + dch1*8;
        vr1a = *(const uint4*)g1;
        vr1b = *(const uint4*)(g1 + NQKV);
    }

#pragma unroll 1
    for (int j = 0; j < nj; j++) {
        // ---- write V(j) regs -> Vt at permuted columns (2 lanes/bank, free) ----
        {
            u32 ra[4] = { vr0a.x, vr0a.y, vr0a.z, vr0a.w };
            u32 rb[4] = { vr0b.x, vr0b.y, vr0b.z, vr0b.w };
            int d0 = dch0*8;
#pragma unroll
            for (int k2 = 0; k2 < 4; k2++) {
                u32 lo = (ra[k2] & 0xffffu) | (rb[k2] << 16);
                u32 hi = (ra[k2] >> 16) | (rb[k2] & 0xffff0000u);
                *(u32*)&Vt[(d0 + 2*k2)     * LV + ccv] = lo;
                *(u32*)&Vt[(d0 + 2*k2 + 1) * LV + ccv] = hi;
            }
            u32 rc[4] = { vr1a.x, vr1a.y, vr1a.z, vr1a.w };
            u32 rd[4] = { vr1b.x, vr1b.y, vr1b.z, vr1b.w };
            d0 = dch1*8;
#pragma unroll
            for (int k2 = 0; k2 < 4; k2++) {
                u32 lo = (rc[k2] & 0xffffu) | (rd[k2] << 16);
                u32 hi = (rc[k2] >> 16) | (rd[k2] & 0xffff0000u);
                *(u32*)&Vt[(d0 + 2*k2)     * LV + ccv] = lo;
                *(u32*)&Vt[(d0 + 2*k2 + 1) * LV + ccv] = hi;
            }
        }
        __syncthreads();   // [A] K(j) landed (vmcnt drain), Vt visible

        // ---- prefetch K(j+1), V(j+1) (hidden behind this iter's compute) ----
        if (j + 1 < nj) {
            const u16* Kbn = Kb + (size_t)(j+1) * 64 * NQKV;
            u16* kl = &Kl[(j+1) & 1][0];
#pragma unroll
            for (int i = 0; i < 4; i++)
                gld16(Kbn + (size_t)krow[i] * NQKV + kgch[i]*8, &kl[(w*16 + i*4) * 128]);
            const u16* Vbn = Vb + (size_t)(j+1) * 64 * NQKV;
            const u16* g0 = Vbn + (size_t)s0v * NQKV + dch0*8;
            vr0a = *(const uint4*)g0;
            vr0b = *(const uint4*)(g0 + NQKV);
            const u16* g1 = Vbn + (size_t)s0v * NQKV + dch1*8;
            vr1a = *(const uint4*)g1;
            vr1b = *(const uint4*)(g1 + NQKV);
        }

        // ---- S^T = mfma(K, Q): one K-fragment read feeds BOTH m-groups ----
        const u16* kl = &Kl[j & 1][0];
        f32x4 S[2][4] = {};
        __builtin_amdgcn_s_setprio(1);
#pragma unroll
        for (int kt = 0; kt < 4; kt++) {
            int p = (kt*4 + quad) ^ (l15 & 7);
#pragma unroll
            for (int nt = 0; nt < 4; nt++) {
                bf16x8 afr = *(const bf16x8*)&kl[(nt*16 + l15)*128 + p*8];
                S[0][nt] = MFMA16(afr, qf[0][kt], S[0][nt]);
                S[1][nt] = MFMA16(afr, qf[1][kt], S[1][nt]);
            }
        }
        __builtin_amdgcn_s_setprio(0);

        // ---- causal mask: only the last two KV-iters are boundary ----
        if (j >= 2*qt) {
            const int sb0 = (j - 2*qt) * 64;
#pragma unroll
            for (int mi = 0; mi < 2; mi++) {
                const int qloc = w*32 + mi*16 + l15;
#pragma unroll
                for (int nt = 0; nt < 4; nt++) {
                    const int sb = sb0 + nt*16 + quad*4;
#pragma unroll
                    for (int r = 0; r < 4; r++)
                        if (sb + r > qloc) S[mi][nt][r] = -1e30f;
                }
            }
        }

        // ---- online softmax per m-group; T13 defer-max (THR=8, log2 domain) ----
        {
            float mx[2];
#pragma unroll
            for (int mi = 0; mi < 2; mi++) {
                float a0 = fmaxf(fmaxf(S[mi][0][0], S[mi][0][1]), fmaxf(S[mi][0][2], S[mi][0][3]));
                float a1 = fmaxf(fmaxf(S[mi][1][0], S[mi][1][1]), fmaxf(S[mi][1][2], S[mi][1][3]));
                float a2 = fmaxf(fmaxf(S[mi][2][0], S[mi][2][1]), fmaxf(S[mi][2][2], S[mi][2][3]));
                float a3 = fmaxf(fmaxf(S[mi][3][0], S[mi][3][1]), fmaxf(S[mi][3][2], S[mi][3][3]));
                float m = fmaxf(fmaxf(a0, a1), fmaxf(a2, a3));
                m = fmaxf(m, __shfl_xor(m, 16, 64));   // across quad pairs
                m = fmaxf(m, __shfl_xor(m, 32, 64));   // across halves
                mx[mi] = m;
            }
            bool grow = __any((mx[0] > mrun[0] + 8.0f) | (mx[1] > mrun[1] + 8.0f));
            float alpha[2] = { 1.0f, 1.0f };
            if (grow) {
#pragma unroll
                for (int mi = 0; mi < 2; mi++) {
                    float mn = fmaxf(mrun[mi], mx[mi]);
                    alpha[mi] = __builtin_amdgcn_exp2f(mrun[mi] - mn);
                    mrun[mi] = mn;
                }
            }
#pragma unroll
            for (int mi = 0; mi < 2; mi++) {
                float rs = 0.0f;
#pragma unroll
                for (int nt = 0; nt < 4; nt++)
#pragma unroll
                    for (int r = 0; r < 4; r++) {
                        float pv = __builtin_amdgcn_exp2f(S[mi][nt][r] - mrun[mi]);
                        S[mi][nt][r] = pv;
                        rs += pv;
                    }
                rs += __shfl_xor(rs, 16, 64);
                rs += __shfl_xor(rs, 32, 64);
                lrun[mi] = lrun[mi] * alpha[mi] + rs;
            }
            if (grow) {
#pragma unroll
                for (int mi = 0; mi < 2; mi++)
#pragma unroll
                    for (int nt = 0; nt < 8; nt++)
                        O[mi][nt] *= alpha[mi];
            }
        }

        // ---- zero-shuffle PV: one Vt read feeds BOTH m-groups ----
        u32 c0[2][4], c1[2][4];
#pragma unroll
        for (int mi = 0; mi < 2; mi++)
#pragma unroll
            for (int nt = 0; nt < 4; nt++) {
                c0[mi][nt] = (u32)f2bf(S[mi][nt][0]) | ((u32)f2bf(S[mi][nt][1]) << 16);
                c1[mi][nt] = (u32)f2bf(S[mi][nt][2]) | ((u32)f2bf(S[mi][nt][3]) << 16);
            }
        __builtin_amdgcn_s_setprio(1);
#pragma unroll
        for (int kt = 0; kt < 2; kt++) {
            uint4 b0, b1;
            b0.x = c0[0][2*kt];   b0.y = c1[0][2*kt];
            b0.z = c0[0][2*kt+1]; b0.w = c1[0][2*kt+1];
            b1.x = c0[1][2*kt];   b1.y = c1[1][2*kt];
            b1.z = c0[1][2*kt+1]; b1.w = c1[1][2*kt+1];
            bf16x8 pf0 = __builtin_bit_cast(bf16x8, b0);
            bf16x8 pf1 = __builtin_bit_cast(bf16x8, b1);
#pragma unroll
            for (int nt = 0; nt < 8; nt++) {
                bf16x8 av = *(const bf16x8*)&Vt[(nt*16 + l15) * LV + kt*32 + quad*8];
                O[0][nt] = MFMA16(av, pf0, O[0][nt]);
                O[1][nt] = MFMA16(av, pf1, O[1][nt]);
            }
        }
        __builtin_amdgcn_s_setprio(0);
        __syncthreads();   // [B] Vt / Kl[j&1] free for next iter's staging
    }

    // ---- epilogue: O^T /= l (lane-local), pack, store b64 ----
#pragma unroll
    for (int mi = 0; mi < 2; mi++) {
        float inv = 1.0f / lrun[mi];
        size_t row = rowbase + qt*128 + w*32 + mi*16 + l15;
        u16* outp = AO + row * HIDDIM + h * HD + quad*4;
#pragma unroll
        for (int nt = 0; nt < 8; nt++) {
            uint2 o;
            o.x = (u32)f2bf(O[mi][nt][0] * inv) | ((u32)f2bf(O[mi][nt][1] * inv) << 16);
            o.y = (u32)f2bf(O[mi][nt][2] * inv) | ((u32)f2bf(O[mi][nt][3] * inv) << 16);
            *(uint2*)(outp + nt*16) = o;
        }
    }
}

extern "C" void kernel_launch(void* const* d_in, const int* in_sizes, int n_in,
                              void* d_out, int out_size, void* d_ws, size_t ws_size,
                              hipStream_t stream) {
    (void)in_sizes; (void)n_in; (void)out_size; (void)ws_size;
    const float* x    = (const float*)d_in[0];
    const float* cosT = (const float*)d_in[1];
    const float* sinT = (const float*)d_in[2];
    const float* Wq   = (const float*)d_in[3];
    const float* Wk   = (const float*)d_in[4];
    const float* Wv   = (const float*)d_in[5];
    const float* Wo   = (const float*)d_in[6];

    char* ws = (char*)d_ws;
    u16* QKV   = (u16*)ws;                                             // 4096*3072 bf16
    u16* xb    = (u16*)(ws + (size_t)MROWS * NQKV * 2);                // 4096*2048 (then attn_out)
    u16* Wqkvt = (u16*)(ws + (size_t)MROWS * NQKV * 2 + (size_t)MROWS * HIDDIM * 2); // 3072*2048
    u16* Wot   = Wqkvt + (size_t)NQKV * KDIM;                          // 2048*2048

    prep_kernel<<<14336, 256, 0, stream>>>(x, xb, Wq, Wk, Wv, Wo, Wqkvt, Wot);
    gemm_bt<1><<<dim3(32, 24), 256, 0, stream>>>(xb, Wqkvt, QKV, NQKV);
    rotary_kernel<<<5120, 256, 0, stream>>>(QKV, cosT, sinT);
    attn_kernel<<<512, 256, 0, stream>>>(QKV, xb);
    gemm_bt<0><<<dim3(32, 16), 256, 0, stream>>>(xb, Wot, d_out, HIDDIM);
}